// Round 16
// baseline (136.822 us; speedup 1.0000x reference)
//
#include <hip/hip_runtime.h>
#include <math.h>

#define NTOK 8192
#define NEMB 8192
#define DIM  256

typedef _Float16 f16x8 __attribute__((ext_vector_type(8)));   // 4 VGPRs
typedef _Float16 f16x4 __attribute__((ext_vector_type(4)));
typedef float    f32x4 __attribute__((ext_vector_type(4)));

// ---------------------------------------------------------------------------
// Kernel A: cast X and C to fp16 (RNE); fused exact fp32 ||x||^2 (one wave
// per 256-elem row; needed for the loss). No cnorm: the codebook rows are
// L2-normalized in setup (||c||^2 = 1 +- 1e-7, which is ~3000x below the
// fp16 dot noise), so distance ranking uses d = 1 - 2 x.c.
// X-branch blocks x<8 init keys to u64-max.
__global__ __launch_bounds__(256) void convert_kernel(
        const float* __restrict__ X, const float* __restrict__ C,
        _Float16* __restrict__ Xh, _Float16* __restrict__ Ch,
        float* __restrict__ xnorm, unsigned long long* __restrict__ keys) {
    const bool isC = (blockIdx.y != 0);
    if (!isC && blockIdx.x < 8) {
        int4 ff = make_int4(-1, -1, -1, -1);
        ((int4*)keys)[blockIdx.x * 512 + threadIdx.x * 2]     = ff;
        ((int4*)keys)[blockIdx.x * 512 + threadIdx.x * 2 + 1] = ff;
    }
    const float* src = isC ? C : X;
    _Float16* dst = isC ? Ch : Xh;
    size_t t = (size_t)blockIdx.x * 256 + threadIdx.x;   // one float4 per thread
    float4 x = *(const float4*)&src[t * 4];
    f16x4 h;
    h[0] = (_Float16)x.x; h[1] = (_Float16)x.y;
    h[2] = (_Float16)x.z; h[3] = (_Float16)x.w;
    *(f16x4*)&dst[t * 4] = h;
    if (!isC) {
        float s = x.x * x.x + x.y * x.y + x.z * x.z + x.w * x.w;
        #pragma unroll
        for (int off = 32; off >= 1; off >>= 1) s += __shfl_xor(s, off);
        if ((threadIdx.x & 63) == 0) xnorm[t >> 6] = s;
    }
}

// ---------------------------------------------------------------------------
// K32-chunk staging (r12-verified): 128x32 fp16 tile = 512 granules of 16B,
// swizzle s(row) = (row + (row>>2)) & 3; frag ds_read_b128 is 2-way banked
// (free per m136), staging lane-contiguous for global_load_lds width-16.
__device__ __forceinline__ int swz(int row) { return (row + (row >> 2)) & 3; }

__device__ __forceinline__ void stage_pair32(
        const _Float16* __restrict__ Ag, const _Float16* __restrict__ Bg,
        _Float16* pair, int t) {
    #pragma unroll
    for (int c = 0; c < 2; ++c) {
        int gr  = c * 256 + t;                   // granule 0..511
        int row = gr >> 2;
        int kg  = (gr & 3) ^ swz(row);           // un-swizzle for global
        __builtin_amdgcn_global_load_lds(
            (const __attribute__((address_space(1))) void*)(Ag + (size_t)row * DIM + kg * 8),
            (__attribute__((address_space(3))) void*)(pair + (size_t)gr * 8), 16, 0, 0);
        __builtin_amdgcn_global_load_lds(
            (const __attribute__((address_space(1))) void*)(Bg + (size_t)row * DIM + kg * 8),
            (__attribute__((address_space(3))) void*)(pair + 4096 + (size_t)gr * 8), 16, 0, 0);
    }
}

__device__ __forceinline__ void compute_pair32(
        const _Float16* pair, f32x4 (&acc)[4][4],
        int wm, int wn, int lrow, int g) {
    const _Float16* Abase = pair;
    const _Float16* Bbase = pair + 4096;
    f16x8 af[4], bf_[4];
    #pragma unroll
    for (int tm = 0; tm < 4; ++tm) {
        int row = wm + tm * 16 + lrow;
        af[tm] = *(const f16x8*)&Abase[(row * 4 + (g ^ swz(row))) * 8];
    }
    #pragma unroll
    for (int tn = 0; tn < 4; ++tn) {
        int row = wn + tn * 16 + lrow;
        bf_[tn] = *(const f16x8*)&Bbase[(row * 4 + (g ^ swz(row))) * 8];
    }
    #pragma unroll
    for (int tm = 0; tm < 4; ++tm)
        #pragma unroll
        for (int tn = 0; tn < 4; ++tn)
            acc[tm][tn] = __builtin_amdgcn_mfma_f32_16x16x32_f16(
                af[tm], bf_[tn], acc[tm][tn], 0, 0, 0);
}

// ---------------------------------------------------------------------------
// Kernel B (r12-verified GEMM core): fp16 distance GEMM (K=256, fp32 accum),
// A=codes, single-barrier double-buffered K32 staging, 32 KB LDS -> 4
// blocks/CU. Epilogue: d = 1 - 2 c.x (codebook unit-norm); packed u64 key =
// bits(d+64)<<32 | code via atomicMin (d in [-50,51] => d+64>0 => float bits
// order-isomorphic; tie -> lower code; order-independent => replay-safe).
// NOTE: plain __launch_bounds__(256) — NO min-waves arg (r2/r13: the 2nd arg
// collapses the register budget below the 64-VGPR accumulator and spills).
__global__ __launch_bounds__(256) void mfma_argmin_kernel(
        const _Float16* __restrict__ Xh, const _Float16* __restrict__ Ch,
        unsigned long long* __restrict__ keys) {
    __shared__ __align__(16) _Float16 lds[16384];   // 32 KB: pair0, pair1

    const int t = threadIdx.x;
    const int wid = t >> 6, lane = t & 63;
    const int tb0 = blockIdx.x * 128;   // token block
    const int cb0 = blockIdx.y * 128;   // code block
    const int wm = (wid >> 1) * 64;     // wave's code offset
    const int wn = (wid & 1) * 64;      // wave's token offset
    const int lrow = lane & 15;
    const int g = lane >> 4;            // quad

    f32x4 acc[4][4];                    // [tm=codes][tn=tokens]
    #pragma unroll
    for (int a = 0; a < 4; ++a)
        #pragma unroll
        for (int b = 0; b < 4; ++b) acc[a][b] = (f32x4)0.0f;

    const _Float16* Ag = Ch + (size_t)cb0 * DIM;   // codes
    const _Float16* Bg = Xh + (size_t)tb0 * DIM;   // tokens

    stage_pair32(Ag, Bg, lds, t);                  // phase 0 -> pair0
    __syncthreads();
    #pragma unroll
    for (int p = 0; p < 8; ++p) {
        _Float16* cur = lds + (p & 1) * 8192;
        if (p < 7) {
            stage_pair32(Ag + (p + 1) * 32, Bg + (p + 1) * 32,
                         lds + ((p + 1) & 1) * 8192, t);
        }
        compute_pair32(cur, acc, wm, wn, lrow, g);
        __syncthreads();
    }

    // ---- epilogue: d = 1 - 2 c.x ; argmin over this block's 128 codes -----
    float* cmb_v = (float*)lds;                    // [128][2]
    int*   cmb_i = (int*)((float*)lds + 256);      // [128][2]

    #pragma unroll
    for (int tn = 0; tn < 4; ++tn) {
        float bv = 1e30f; int bi = 0x7fffffff;
        #pragma unroll
        for (int tm = 0; tm < 4; ++tm) {
            #pragma unroll
            for (int reg = 0; reg < 4; ++reg) {
                float d = fmaf(-2.0f, acc[tm][tn][reg], 1.0f);
                int code = cb0 + wm + tm * 16 + g * 4 + reg;  // ascending -> strict <
                if (d < bv) { bv = d; bi = code; }
            }
        }
        #pragma unroll
        for (int off = 16; off <= 32; off <<= 1) {  // reduce over the 4 quads
            float ov = __shfl_xor(bv, off);
            int   oi = __shfl_xor(bi, off);
            if (ov < bv || (ov == bv && oi < bi)) { bv = ov; bi = oi; }
        }
        if (g == 0) {
            int tl = wn + tn * 16 + lrow;           // token-local 0..127
            cmb_v[tl * 2 + (wid >> 1)] = bv;
            cmb_i[tl * 2 + (wid >> 1)] = bi;
        }
    }
    __syncthreads();
    if (t < 128) {
        float v0 = cmb_v[t * 2], v1 = cmb_v[t * 2 + 1];
        int   i0 = cmb_i[t * 2], i1 = cmb_i[t * 2 + 1];
        bool tk = (v1 < v0) || (v1 == v0 && i1 < i0);
        float bv = tk ? v1 : v0;
        int   bi = tk ? i1 : i0;
        unsigned long long key =
            ((unsigned long long)__builtin_bit_cast(unsigned, bv + 64.0f) << 32)
            | (unsigned)bi;
        atomicMin(&keys[tb0 + t], key);
    }
}

// ---------------------------------------------------------------------------
// Kernel C: gather + stats in ONE dispatch (257 blocks). keys[] is final at
// this kernel boundary, and keys+xnorm determine everything downstream:
//  - blocks 0..255: gather 32 tokens each (C row -> out). No atomics.
//  - block 256 (stats, runs concurrently): LDS histogram of all 8192 keys,
//    entropy + loss = sum(d + xnorm), writes the two scalars.
__global__ __launch_bounds__(256) void gather_stats_kernel(
        const float* __restrict__ C, const unsigned long long* __restrict__ keys,
        const float* __restrict__ xnorm, float* __restrict__ out) {
    const int t = threadIdx.x;
    if (blockIdx.x < 256) {
        __shared__ int idx_lds[32];
        const int m0 = blockIdx.x * 32;
        if (t < 32) idx_lds[t] = (int)(unsigned)keys[m0 + t];
        __syncthreads();
        const int wid = t >> 6, lane = t & 63;
        #pragma unroll
        for (int r = 0; r < 8; ++r) {
            int token = m0 + wid * 8 + r;
            int e = idx_lds[wid * 8 + r];
            float4 q = *(const float4*)&C[(size_t)e * DIM + lane * 4];
            *(float4*)&out[(size_t)token * DIM + lane * 4] = q;
        }
        return;
    }
    // ---- stats block ------------------------------------------------------
    __shared__ int hist[NEMB];          // 32 KB
    __shared__ double she[4];
    __shared__ float  shs[4];
    for (int i = t; i < NEMB; i += 256) hist[i] = 0;
    __syncthreads();
    float ls = 0.0f;
    #pragma unroll 1
    for (int i = t; i < NTOK; i += 256) {
        unsigned long long k = keys[i];
        atomicAdd(&hist[(int)(unsigned)k], 1);
        float d = __builtin_bit_cast(float, (unsigned)(k >> 32)) - 64.0f;
        ls += d + xnorm[i];             // ||x - c||^2 for token i
    }
    __syncthreads();
    double local = 0.0;
    #pragma unroll 1
    for (int e = t; e < NEMB; e += 256) {
        float p = (float)hist[e] * (1.0f / (float)NTOK);
        local += (double)(p * logf(p + 1e-10f));
    }
    int lane = t & 63, wid = t >> 6;
    #pragma unroll
    for (int off = 32; off >= 1; off >>= 1) {
        local += __shfl_xor(local, off);
        ls    += __shfl_xor(ls, off);
    }
    if (lane == 0) { she[wid] = local; shs[wid] = ls; }
    __syncthreads();
    if (t == 0) {
        double ent = she[0] + she[1] + she[2] + she[3];
        float  ssq = shs[0] + shs[1] + shs[2] + shs[3];
        out[(size_t)NTOK * DIM]     = 1.25f * ssq / (float)((size_t)NTOK * DIM);
        out[(size_t)NTOK * DIM + 1] = expf((float)(-ent));
    }
}

// ---------------------------------------------------------------------------
extern "C" void kernel_launch(void* const* d_in, const int* in_sizes, int n_in,
                              void* d_out, int out_size, void* d_ws, size_t ws_size,
                              hipStream_t stream) {
    const float* X = (const float*)d_in[0];   // [32,256,256] fp32
    const float* C = (const float*)d_in[1];   // [8192,256]   fp32
    float* out = (float*)d_out;

    char* ws = (char*)d_ws;
    size_t o = 0;
    _Float16* Xh = (_Float16*)(ws + o); o += (size_t)NTOK * DIM * 2;
    _Float16* Ch = (_Float16*)(ws + o); o += (size_t)NEMB * DIM * 2;
    float* xnorm = (float*)(ws + o); o += (size_t)NTOK * 4;
    unsigned long long* keys = (unsigned long long*)(ws + o); o += (size_t)NTOK * 8;

    convert_kernel<<<dim3(NTOK * DIM / 4 / 256, 2), 256, 0, stream>>>(
        X, C, Xh, Ch, xnorm, keys);
    mfma_argmin_kernel<<<dim3(NTOK / 128, NEMB / 128), 256, 0, stream>>>(
        Xh, Ch, keys);
    gather_stats_kernel<<<257, 256, 0, stream>>>(
        C, keys, xnorm, out);
}

// Round 17
// 133.303 us; speedup vs baseline: 1.0264x; 1.0264x over previous
//
#include <hip/hip_runtime.h>
#include <math.h>

#define NTOK 8192
#define NEMB 8192
#define DIM  256

typedef _Float16 f16x8 __attribute__((ext_vector_type(8)));   // 4 VGPRs
typedef _Float16 f16x4 __attribute__((ext_vector_type(4)));
typedef float    f32x4 __attribute__((ext_vector_type(4)));

// ---------------------------------------------------------------------------
// Kernel A: cast X and C to fp16 (RNE); fused exact fp32 ||c||^2 and ||x||^2
// (each wave covers exactly one 256-elem row). C-branch blocks x<8 zero
// counts; X-branch blocks x<8 init keys to u64-max.
__global__ __launch_bounds__(256) void convert_kernel(
        const float* __restrict__ X, const float* __restrict__ C,
        _Float16* __restrict__ Xh, _Float16* __restrict__ Ch,
        float* __restrict__ cnorm, float* __restrict__ xnorm,
        unsigned long long* __restrict__ keys, int* __restrict__ counts) {
    const bool isC = (blockIdx.y != 0);
    if (isC && blockIdx.x < 8) {
        ((int4*)counts)[blockIdx.x * 256 + threadIdx.x] = make_int4(0, 0, 0, 0);
    }
    if (!isC && blockIdx.x < 8) {
        int4 ff = make_int4(-1, -1, -1, -1);
        ((int4*)keys)[blockIdx.x * 512 + threadIdx.x * 2]     = ff;
        ((int4*)keys)[blockIdx.x * 512 + threadIdx.x * 2 + 1] = ff;
    }
    const float* src = isC ? C : X;
    _Float16* dst = isC ? Ch : Xh;
    size_t t = (size_t)blockIdx.x * 256 + threadIdx.x;   // one float4 per thread
    float4 x = *(const float4*)&src[t * 4];
    f16x4 h;
    h[0] = (_Float16)x.x; h[1] = (_Float16)x.y;
    h[2] = (_Float16)x.z; h[3] = (_Float16)x.w;
    *(f16x4*)&dst[t * 4] = h;
    float s = x.x * x.x + x.y * x.y + x.z * x.z + x.w * x.w;
    #pragma unroll
    for (int off = 32; off >= 1; off >>= 1) s += __shfl_xor(s, off);
    if ((threadIdx.x & 63) == 0) {
        if (isC) cnorm[t >> 6] = s; else xnorm[t >> 6] = s;
    }
}

// ---------------------------------------------------------------------------
// K32-chunk staging (r12-verified): 128x32 fp16 tile = 512 granules of 16B,
// swizzle s(row) = (row + (row>>2)) & 3; frag ds_read_b128 is 2-way banked
// (free per m136), staging lane-contiguous for global_load_lds width-16.
__device__ __forceinline__ int swz(int row) { return (row + (row >> 2)) & 3; }

__device__ __forceinline__ void stage_pair32(
        const _Float16* __restrict__ Ag, const _Float16* __restrict__ Bg,
        _Float16* pair, int t) {
    #pragma unroll
    for (int c = 0; c < 2; ++c) {
        int gr  = c * 256 + t;                   // granule 0..511
        int row = gr >> 2;
        int kg  = (gr & 3) ^ swz(row);           // un-swizzle for global
        __builtin_amdgcn_global_load_lds(
            (const __attribute__((address_space(1))) void*)(Ag + (size_t)row * DIM + kg * 8),
            (__attribute__((address_space(3))) void*)(pair + (size_t)gr * 8), 16, 0, 0);
        __builtin_amdgcn_global_load_lds(
            (const __attribute__((address_space(1))) void*)(Bg + (size_t)row * DIM + kg * 8),
            (__attribute__((address_space(3))) void*)(pair + 4096 + (size_t)gr * 8), 16, 0, 0);
    }
}

__device__ __forceinline__ void compute_pair32(
        const _Float16* pair, f32x4 (&acc)[4][4],
        int wm, int wn, int lrow, int g) {
    const _Float16* Abase = pair;
    const _Float16* Bbase = pair + 4096;
    f16x8 af[4], bf_[4];
    #pragma unroll
    for (int tm = 0; tm < 4; ++tm) {
        int row = wm + tm * 16 + lrow;
        af[tm] = *(const f16x8*)&Abase[(row * 4 + (g ^ swz(row))) * 8];
    }
    #pragma unroll
    for (int tn = 0; tn < 4; ++tn) {
        int row = wn + tn * 16 + lrow;
        bf_[tn] = *(const f16x8*)&Bbase[(row * 4 + (g ^ swz(row))) * 8];
    }
    #pragma unroll
    for (int tm = 0; tm < 4; ++tm)
        #pragma unroll
        for (int tn = 0; tn < 4; ++tn)
            acc[tm][tn] = __builtin_amdgcn_mfma_f32_16x16x32_f16(
                af[tm], bf_[tn], acc[tm][tn], 0, 0, 0);
}

// ---------------------------------------------------------------------------
// Kernel B (r12-verified, best measured: 53.5us, 84 VGPR, MfmaUtil 26%):
// fp16 distance GEMM (K=256, fp32 accum), A=codes (argmin over C/D rows),
// single-barrier double-buffered K32 staging, 32 KB LDS -> 4 blocks/CU.
// The cn[16] register preload is load-bearing: r16 showed that removing it
// lets the allocator collapse to a 68-VGPR low-ILP schedule (GEMM +18%).
// Epilogue: packed u64 key = bits(d+64)<<32 | code via atomicMin
// (d in [-50,51] => d+64>0 => float bits order-isomorphic; tie -> lower
// code; min is order-independent => graph-replay-safe).
// NOTE: plain __launch_bounds__(256) — NO min-waves arg (r2/r13: the 2nd arg
// collapses the register budget below the 64-VGPR accumulator and spills).
__global__ __launch_bounds__(256) void mfma_argmin_kernel(
        const _Float16* __restrict__ Xh, const _Float16* __restrict__ Ch,
        const float* __restrict__ cnorm,
        unsigned long long* __restrict__ keys) {
    __shared__ __align__(16) _Float16 lds[16384];   // 32 KB: pair0, pair1

    const int t = threadIdx.x;
    const int wid = t >> 6, lane = t & 63;
    const int tb0 = blockIdx.x * 128;   // token block
    const int cb0 = blockIdx.y * 128;   // code block
    const int wm = (wid >> 1) * 64;     // wave's code offset
    const int wn = (wid & 1) * 64;      // wave's token offset
    const int lrow = lane & 15;
    const int g = lane >> 4;            // quad

    float cn[16];
    #pragma unroll
    for (int tm = 0; tm < 4; ++tm)
        #pragma unroll
        for (int reg = 0; reg < 4; ++reg)
            cn[tm * 4 + reg] = cnorm[cb0 + wm + tm * 16 + g * 4 + reg];

    f32x4 acc[4][4];                    // [tm=codes][tn=tokens]
    #pragma unroll
    for (int a = 0; a < 4; ++a)
        #pragma unroll
        for (int b = 0; b < 4; ++b) acc[a][b] = (f32x4)0.0f;

    const _Float16* Ag = Ch + (size_t)cb0 * DIM;   // codes
    const _Float16* Bg = Xh + (size_t)tb0 * DIM;   // tokens

    stage_pair32(Ag, Bg, lds, t);                  // phase 0 -> pair0
    __syncthreads();
    #pragma unroll
    for (int p = 0; p < 8; ++p) {
        _Float16* cur = lds + (p & 1) * 8192;
        if (p < 7) {
            stage_pair32(Ag + (p + 1) * 32, Bg + (p + 1) * 32,
                         lds + ((p + 1) & 1) * 8192, t);
        }
        compute_pair32(cur, acc, wm, wn, lrow, g);
        __syncthreads();
    }

    // ---- epilogue: d = ||c||^2 - 2 c.x ; argmin over this block's 128 codes
    float* cmb_v = (float*)lds;                    // [128][2]
    int*   cmb_i = (int*)((float*)lds + 256);      // [128][2]

    #pragma unroll
    for (int tn = 0; tn < 4; ++tn) {
        float bv = 1e30f; int bi = 0x7fffffff;
        #pragma unroll
        for (int tm = 0; tm < 4; ++tm) {
            #pragma unroll
            for (int reg = 0; reg < 4; ++reg) {
                float d = fmaf(-2.0f, acc[tm][tn][reg], cn[tm * 4 + reg]);
                int code = cb0 + wm + tm * 16 + g * 4 + reg;  // ascending -> strict <
                if (d < bv) { bv = d; bi = code; }
            }
        }
        #pragma unroll
        for (int off = 16; off <= 32; off <<= 1) {  // reduce over the 4 quads
            float ov = __shfl_xor(bv, off);
            int   oi = __shfl_xor(bi, off);
            if (ov < bv || (ov == bv && oi < bi)) { bv = ov; bi = oi; }
        }
        if (g == 0) {
            int tl = wn + tn * 16 + lrow;           // token-local 0..127
            cmb_v[tl * 2 + (wid >> 1)] = bv;
            cmb_i[tl * 2 + (wid >> 1)] = bi;
        }
    }
    __syncthreads();
    if (t < 128) {
        float v0 = cmb_v[t * 2], v1 = cmb_v[t * 2 + 1];
        int   i0 = cmb_i[t * 2], i1 = cmb_i[t * 2 + 1];
        bool tk = (v1 < v0) || (v1 == v0 && i1 < i0);
        float bv = tk ? v1 : v0;
        int   bi = tk ? i1 : i0;
        unsigned long long key =
            ((unsigned long long)__builtin_bit_cast(unsigned, bv + 64.0f) << 32)
            | (unsigned)bi;
        atomicMin(&keys[tb0 + t], key);
    }
}

// ---------------------------------------------------------------------------
// Kernel C: unpack keys -> idx + distance, histogram via device atomics,
// gather C rows -> out, per-block loss partial (||x-c||^2 = xnorm + d) to
// psum. 256 blocks x 32 tokens.
__global__ __launch_bounds__(256) void gather_kernel(
        const float* __restrict__ C, const unsigned long long* __restrict__ keys,
        const float* __restrict__ xnorm, int* __restrict__ counts,
        float* __restrict__ out, float* __restrict__ psum) {
    __shared__ int idx_lds[32];
    const int m0 = blockIdx.x * 32;
    const int t = threadIdx.x;
    if (t < 32) {
        unsigned long long k = keys[m0 + t];
        int bi  = (int)(unsigned)k;
        float d = __builtin_bit_cast(float, (unsigned)(k >> 32)) - 64.0f;
        idx_lds[t] = bi;
        atomicAdd(&counts[bi], 1);
        float lt = d + xnorm[m0 + t];               // ||x - c||^2 for this token
        #pragma unroll
        for (int off = 1; off < 32; off <<= 1) lt += __shfl_xor(lt, off);
        if (t == 0) psum[blockIdx.x] = lt;
    }
    __syncthreads();
    const int wid = t >> 6, lane = t & 63;
    #pragma unroll
    for (int r = 0; r < 8; ++r) {
        int token = m0 + wid * 8 + r;
        int e = idx_lds[wid * 8 + r];
        float4 q = *(const float4*)&C[(size_t)e * DIM + lane * 4];
        *(float4*)&out[(size_t)token * DIM + lane * 4] = q;
    }
}

// ---------------------------------------------------------------------------
// Kernel D: entropy over the 8192-bin histogram + loss. Single small block,
// plain loads (visibility via kernel boundary).
__global__ __launch_bounds__(256) void finalize_kernel(
        const int* __restrict__ counts, const float* __restrict__ psum,
        float* __restrict__ out) {
    const int t = threadIdx.x;
    double local = 0.0;
    #pragma unroll 1
    for (int e = t; e < NEMB; e += 256) {
        float p = (float)counts[e] * (1.0f / (float)NTOK);
        local += (double)(p * logf(p + 1e-10f));
    }
    float ls = psum[t];          // 256 threads, 256 partial sums
    #pragma unroll
    for (int off = 32; off >= 1; off >>= 1) {
        local += __shfl_xor(local, off);
        ls    += __shfl_xor(ls, off);
    }
    __shared__ double she[4];
    __shared__ float  shs[4];
    int lane = t & 63, wid = t >> 6;
    if (lane == 0) { she[wid] = local; shs[wid] = ls; }
    __syncthreads();
    if (t == 0) {
        double ent = she[0] + she[1] + she[2] + she[3];
        float  ssq = shs[0] + shs[1] + shs[2] + shs[3];
        out[(size_t)NTOK * DIM]     = 1.25f * ssq / (float)((size_t)NTOK * DIM);
        out[(size_t)NTOK * DIM + 1] = expf((float)(-ent));
    }
}

// ---------------------------------------------------------------------------
extern "C" void kernel_launch(void* const* d_in, const int* in_sizes, int n_in,
                              void* d_out, int out_size, void* d_ws, size_t ws_size,
                              hipStream_t stream) {
    const float* X = (const float*)d_in[0];   // [32,256,256] fp32
    const float* C = (const float*)d_in[1];   // [8192,256]   fp32
    float* out = (float*)d_out;

    char* ws = (char*)d_ws;
    size_t o = 0;
    _Float16* Xh = (_Float16*)(ws + o); o += (size_t)NTOK * DIM * 2;
    _Float16* Ch = (_Float16*)(ws + o); o += (size_t)NEMB * DIM * 2;
    float* cnorm = (float*)(ws + o); o += (size_t)NEMB * 4;
    float* xnorm = (float*)(ws + o); o += (size_t)NTOK * 4;
    unsigned long long* keys = (unsigned long long*)(ws + o); o += (size_t)NTOK * 8;
    int* counts  = (int*)(ws + o);   o += (size_t)NEMB * 4;
    float* psum  = (float*)(ws + o);

    convert_kernel<<<dim3(NTOK * DIM / 4 / 256, 2), 256, 0, stream>>>(
        X, C, Xh, Ch, cnorm, xnorm, keys, counts);
    mfma_argmin_kernel<<<dim3(NTOK / 128, NEMB / 128), 256, 0, stream>>>(
        Xh, Ch, cnorm, keys);
    gather_kernel<<<256, 256, 0, stream>>>(
        C, keys, xnorm, counts, out, psum);
    finalize_kernel<<<1, 256, 0, stream>>>(counts, psum, out);
}